// Round 7
// baseline (1659.852 us; speedup 1.0000x reference)
//
#include <hip/hip_runtime.h>
#include <stdint.h>

#define BB 64
#define TT 128
#define INF 257
#define KP 288
#define HH 1024
#define G4 4096
#define NWRK 192

typedef _Float16 half8 __attribute__((ext_vector_type(8)));
typedef float f4 __attribute__((ext_vector_type(4)));

__device__ __forceinline__ f4 mfma16(half8 a, half8 b, f4 c) {
  return __builtin_amdgcn_mfma_f32_16x16x32_f16(a, b, c, 0, 0, 0);
}

// async global->LDS, 16B per lane; LDS dest is wave-uniform base + lane*16
__device__ __forceinline__ void gld_lds16(const void* g, void* l) {
  auto gp = reinterpret_cast<__attribute__((address_space(1))) void*>(reinterpret_cast<uintptr_t>(g));
  auto lp = reinterpret_cast<__attribute__((address_space(3))) void*>(reinterpret_cast<uintptr_t>(l));
  __builtin_amdgcn_global_load_lds(gp, lp, 16, 0, 0);
}

__device__ __forceinline__ unsigned aload(unsigned* p) {
  return __hip_atomic_load(p, __ATOMIC_RELAXED, __HIP_MEMORY_SCOPE_AGENT);
}

// ---------- prep kernels ----------
__global__ __launch_bounds__(256) void k_cast_X(const float* __restrict__ X, _Float16* __restrict__ Xt) {
  int o = blockIdx.x * 256 + threadIdx.x;
  if (o >= TT * BB * KP) return;
  int k = o % KP, m = o / KP;
  int t = m >> 6, b = m & 63;
  float v = (k < INF) ? X[((size_t)b * TT + t) * INF + k] : 0.f;
  Xt[o] = (_Float16)v;
}

__global__ __launch_bounds__(256) void k_cast_padW(const float* __restrict__ W, _Float16* __restrict__ Wp) {
  int o = blockIdx.x * 256 + threadIdx.x;
  if (o >= G4 * KP) return;
  int k = o % KP, n = o / KP;
  Wp[o] = (_Float16)((k < INF) ? W[(size_t)n * INF + k] : 0.f);
}

__global__ __launch_bounds__(256) void k_cast(const float* __restrict__ W, _Float16* __restrict__ Wh, int n) {
  int o = blockIdx.x * 256 + threadIdx.x;
  if (o < n) Wh[o] = (_Float16)W[o];
}

__global__ __launch_bounds__(256) void k_bias(const float* __restrict__ a, const float* __restrict__ b,
                                              const float* __restrict__ c, const float* __restrict__ d,
                                              float* __restrict__ b0, float* __restrict__ b1) {
  int o = blockIdx.x * 256 + threadIdx.x;
  if (o < G4) { b0[o] = a[o] + b[o]; b1[o] = c[o] + d[o]; }
}

// ---------- worker GEMM tile: C[128x128] = A[128xK] @ Bw[128xK]^T + bias ----------
// 512 thr / 8 waves; wave w covers (wm=(w>>2)*64, wn=(w&3)*32); acc[4][2] = 32 VGPRs.
__device__ __forceinline__ void wtile(const _Float16* __restrict__ A, int lda,
                                      const _Float16* __restrict__ Bw, int ldb,
                                      const float* __restrict__ bias, _Float16* __restrict__ C,
                                      int m0, int n0, int K,
                                      _Float16* As, _Float16* Bs, int tid) {
  const int w = tid >> 6, lane = tid & 63;
  const int q = lane >> 4, ml = lane & 15;
  const int wm = (w >> 2) * 64, wn = (w & 3) * 32;
  f4 acc[4][2] = {};
  const int iters = K >> 5;
  for (int kt = 0; kt < iters; ++kt) {
    __syncthreads();
    {
      int kc = w >> 1, r0 = (w & 1) * 64;  // wave stages 64 chunks: [kc][r0+lane][8]
      gld_lds16(A + (size_t)(m0 + r0 + lane) * lda + kt * 32 + kc * 8, (char*)As + (size_t)(w * 64) * 16);
      gld_lds16(Bw + (size_t)(n0 + r0 + lane) * ldb + kt * 32 + kc * 8, (char*)Bs + (size_t)(w * 64) * 16);
    }
    __syncthreads();
    half8 af[4], bf[2];
#pragma unroll
    for (int tm = 0; tm < 4; ++tm) af[tm] = *(const half8*)(As + ((size_t)q * 128 + wm + tm * 16 + ml) * 8);
#pragma unroll
    for (int tn = 0; tn < 2; ++tn) bf[tn] = *(const half8*)(Bs + ((size_t)q * 128 + wn + tn * 16 + ml) * 8);
#pragma unroll
    for (int tm = 0; tm < 4; ++tm)
#pragma unroll
      for (int tn = 0; tn < 2; ++tn)
        acc[tm][tn] = mfma16(af[tm], bf[tn], acc[tm][tn]);
  }
#pragma unroll
  for (int tn = 0; tn < 2; ++tn) {
    int n = n0 + wn + tn * 16 + ml;
    float bv = bias[n];
#pragma unroll
    for (int tm = 0; tm < 4; ++tm)
#pragma unroll
      for (int r = 0; r < 4; ++r) {
        int m = m0 + wm + tm * 16 + q * 4 + r;
        C[(size_t)m * G4 + n] = (_Float16)(acc[tm][tn][r] + bv);
      }
  }
}

// ---------- persistent recurrence (one layer), mg-paired: 128 WGs x 512 thr ----------
// WG idx: ug = idx&63 (units [ug*16..+16) x 4 gates), mgp = idx>>6 (rows [mgp*32..+32)).
// Wave w = K-eighth. Release: h via returning atomic exchange (at IC) -> waitcnt ->
// syncthreads -> bump cy[(mgp,ug>>3)]. Consumer wave w spins cy[(mgp,w)] >= 8t.
// xg gating: cx[t>>1] == 32 (worker tiles cover a t-pair).
__device__ __forceinline__ void rec_layer(const _Float16* __restrict__ xg, const _Float16* Whh,
                                          _Float16* y, unsigned* cy, unsigned* cx,
                                          int idx, int tid, float (*gl)[4][32][16]) {
  const int w = tid >> 6, lane = tid & 63;
  const int q = lane >> 4, ml = lane & 15;
  const int ug = idx & 63, mgp = idx >> 6;
  const int u0 = ug * 16, b0 = mgp * 32;
  const int brow = tid >> 4, u = tid & 15;   // 512 thr = 32 rows x 16 units
  const int bi = b0 + brow, col = u0 + u;

  half8 bf[4][4];  // B frags once: row = tn*HH+u0+ml, k = w*128 + kt*32 + q*8
#pragma unroll
  for (int tn = 0; tn < 4; ++tn)
#pragma unroll
    for (int kt = 0; kt < 4; ++kt)
      bf[tn][kt] = *(const half8*)(Whh + (size_t)(tn * HH + u0 + ml) * HH + w * 128 + kt * 32 + q * 8);

  unsigned* myArr = cy + (size_t)(mgp * 8 + (ug >> 3)) * 16;
  unsigned* mySpin = cy + (size_t)(mgp * 8 + w) * 16;
  float c_reg = 0.f;

  for (int t = 0; t < TT; ++t) {
    if (lane == 0) {  // xg[t] ready? (workers run far ahead in steady state)
      unsigned* cxp = cx + (size_t)(t >> 1) * 16;
      while (aload(cxp) < 32u) __builtin_amdgcn_s_sleep(1);
    }
    asm volatile("" ::: "memory");
    const _Float16* xp = xg + ((size_t)t * BB + bi) * G4 + col;
    _Float16 xv0 = xp[0], xv1 = xp[HH], xv2 = xp[2 * HH], xv3 = xp[3 * HH];
    f4 acc[4][2] = {};
    if (t > 0) {
      if (lane == 0) {
        unsigned tgt = 8u * (unsigned)t;
        while (aload(mySpin) < tgt) __builtin_amdgcn_s_sleep(1);
      }
      asm volatile("" ::: "memory");
      const _Float16* hp = y + ((size_t)(t - 1) * BB + b0 + ml) * HH + w * 128 + q * 8;
      half8 af[2][4];
#pragma unroll
      for (int tm = 0; tm < 2; ++tm)
#pragma unroll
        for (int kt = 0; kt < 4; ++kt)
          af[tm][kt] = *(const half8*)(hp + (size_t)tm * 16 * HH + kt * 32);
#pragma unroll
      for (int kt = 0; kt < 4; ++kt)
#pragma unroll
        for (int tm = 0; tm < 2; ++tm)
#pragma unroll
          for (int tn = 0; tn < 4; ++tn)
            acc[tn][tm] = mfma16(af[tm][kt], bf[tn][kt], acc[tn][tm]);
    }
    // K-partials to LDS; C/D: unit = ml, row-in-tile = q*4+r
#pragma unroll
    for (int tn = 0; tn < 4; ++tn)
#pragma unroll
      for (int tm = 0; tm < 2; ++tm)
#pragma unroll
        for (int r = 0; r < 4; ++r)
          gl[w][tn][tm * 16 + q * 4 + r][ml] = acc[tn][tm][r];
    __syncthreads();

    float g0 = (float)xv0, g1 = (float)xv1, g2 = (float)xv2, g3 = (float)xv3;
#pragma unroll
    for (int kw = 0; kw < 8; ++kw) {
      g0 += gl[kw][0][brow][u]; g1 += gl[kw][1][brow][u];
      g2 += gl[kw][2][brow][u]; g3 += gl[kw][3][brow][u];
    }
    float I = 1.f / (1.f + __expf(-g0));
    float F = 1.f / (1.f + __expf(-g1));
    float G = tanhf(g2);
    float O = 1.f / (1.f + __expf(-g3));
    c_reg = F * c_reg + I * G;
    unsigned hv = (unsigned)__builtin_bit_cast(unsigned short, (_Float16)(O * tanhf(c_reg)));
    unsigned other = (unsigned)__shfl_xor((int)hv, 1);
    if ((tid & 1) == 0) {  // returning atomic => executes at IC => visible when acked
      unsigned word = hv | (other << 16);
      (void)__hip_atomic_exchange((unsigned*)(y + ((size_t)t * BB + bi) * HH + col), word,
                                  __ATOMIC_RELAXED, __HIP_MEMORY_SCOPE_AGENT);
    }
    __builtin_amdgcn_s_waitcnt(0);  // exchange acks back => h at IC
    __syncthreads();                // whole WG done (also protects gl reuse)
    if (tid == 0) atomicAdd(myArr, 1u);
  }
}

// ---------- mega kernel: layer0 rec (128) + layer1 rec (128) + GEMM workers (192) ----------
// bar layout (u32): cy1 @0 (16x16), cy2 @256, cx0 @512 (64x16), cx1 @1536.
__global__ __launch_bounds__(512, 4) void k_mega(const _Float16* __restrict__ Xt,
                                                 const _Float16* __restrict__ W0p,
                                                 const _Float16* Whh0, const _Float16* __restrict__ Wih1,
                                                 const _Float16* Whh1,
                                                 const float* __restrict__ b0, const float* __restrict__ b1,
                                                 _Float16* xg0, _Float16* xg1,
                                                 _Float16* y1, _Float16* y2, unsigned* bar) {
  __shared__ __align__(16) char smraw[65536];  // union: rec gl (64 KB) / worker As+Bs (16 KB)
  const int bid = blockIdx.x, tid = threadIdx.x;
  unsigned* cy1 = bar;
  unsigned* cy2 = bar + 256;
  unsigned* cx0 = bar + 512;
  unsigned* cx1 = bar + 1536;

  if (bid < 256) {
    float (*gl)[4][32][16] = (float(*)[4][32][16])smraw;
    const int layer = bid >> 7, idx = bid & 127;
    rec_layer(layer ? xg1 : xg0, layer ? Whh1 : Whh0, layer ? y2 : y1,
              layer ? cy2 : cy1, layer ? cx1 : cx0, idx, tid, gl);
    return;
  }

  // ---- worker ----
  _Float16* As = (_Float16*)smraw;
  _Float16* Bs = (_Float16*)(smraw + 8192);
  const int wid = bid - 256;
  // phase 0: xg0 tiles (dep-free). j -> tp = j>>5, n0 = (j&31)*128 (tp-ordered round-robin)
  for (int j = wid; j < 2048; j += NWRK) {
    const int tp = j >> 5, n0 = (j & 31) * 128;
    wtile(Xt, KP, W0p, KP, b0, xg0, tp * 128, n0, KP, As, Bs, tid);
    __syncthreads();  // all waves' stores drained (vmcnt0 before barrier)
    if (tid == 0) { __threadfence(); atomicAdd(cx0 + (size_t)tp * 16, 1u); }  // wbl2 -> IC, then bump
  }
  // phase 1: xg1 tiles, gated on y1[2tp+1] (all 16 cy1 counters >= 16(tp+1))
  for (int j = wid; j < 2048; j += NWRK) {
    const int tp = j >> 5, n0 = (j & 31) * 128;
    if (tid < 64) {  // wave 0 polls the 16 counters lane-parallel; others gate on wtile's barrier
      unsigned tgt = 16u * (unsigned)(tp + 1);
      unsigned* cp = cy1 + (size_t)(tid & 15) * 16;
      for (;;) {
        unsigned v = aload(cp);
        if (__all((tid < 16) ? (int)(v >= tgt) : 1)) break;
        __builtin_amdgcn_s_sleep(2);
      }
    }
    wtile(y1, HH, Wih1, HH, b1, xg1, tp * 128, n0, HH, As, Bs, tid);
    __syncthreads();
    if (tid == 0) { __threadfence(); atomicAdd(cx1 + (size_t)tp * 16, 1u); }
  }
}

// ---------- output head ----------
__global__ __launch_bounds__(256) void k_out(const _Float16* __restrict__ y2, const float* __restrict__ Wy,
                                             const float* __restrict__ by, float* __restrict__ out) {
  int gw = blockIdx.x * 4 + (threadIdx.x >> 6);
  int lane = threadIdx.x & 63;
  int t = gw >> 6, b = gw & 63;
  const _Float16* row = y2 + (size_t)gw * HH;
  float p0 = 0.f, p1 = 0.f;
#pragma unroll
  for (int i = 0; i < 16; ++i) {
    int k = i * 64 + lane;
    float v = tanhf((float)row[k]);
    p0 += v * Wy[k];
    p1 += v * Wy[HH + k];
  }
  for (int off = 32; off > 0; off >>= 1) {
    p0 += __shfl_down(p0, off);
    p1 += __shfl_down(p1, off);
  }
  if (lane == 0) {
    out[((size_t)b * TT + t) * 2 + 0] = p0 + by[0];
    out[((size_t)b * TT + t) * 2 + 1] = p1 + by[1];
  }
}

extern "C" void kernel_launch(void* const* d_in, const int* in_sizes, int n_in,
                              void* d_out, int out_size, void* d_ws, size_t ws_size,
                              hipStream_t stream) {
  (void)in_sizes; (void)n_in; (void)out_size; (void)ws_size;
  const float* X    = (const float*)d_in[0];
  const float* Wih0 = (const float*)d_in[3];
  const float* Whh0 = (const float*)d_in[4];
  const float* bih0 = (const float*)d_in[5];
  const float* bhh0 = (const float*)d_in[6];
  const float* Wih1 = (const float*)d_in[7];
  const float* Whh1 = (const float*)d_in[8];
  const float* bih1 = (const float*)d_in[9];
  const float* bhh1 = (const float*)d_in[10];
  const float* Wy   = (const float*)d_in[11];
  const float* by   = (const float*)d_in[12];
  float* out = (float*)d_out;

  char* p = (char*)d_ws;
  auto carve = [&](size_t bytes) { char* r = p; p += (bytes + 255) & ~(size_t)255; return r; };
  _Float16* Xt    = (_Float16*)carve((size_t)TT * BB * KP * 2);
  _Float16* W0p   = (_Float16*)carve((size_t)G4 * KP * 2);
  _Float16* Whh0h = (_Float16*)carve((size_t)G4 * HH * 2);
  _Float16* Wih1h = (_Float16*)carve((size_t)G4 * HH * 2);
  _Float16* Whh1h = (_Float16*)carve((size_t)G4 * HH * 2);
  float* b0 = (float*)carve((size_t)G4 * 4);
  float* b1 = (float*)carve((size_t)G4 * 4);
  _Float16* xg0 = (_Float16*)carve((size_t)TT * BB * G4 * 2);
  _Float16* xg1 = (_Float16*)carve((size_t)TT * BB * G4 * 2);
  _Float16* y1  = (_Float16*)carve((size_t)TT * BB * HH * 2);
  _Float16* y2  = (_Float16*)carve((size_t)TT * BB * HH * 2);
  unsigned* bar = (unsigned*)carve(12288);

  hipMemsetAsync(bar, 0, 12288, stream);  // counters zero (ws is poisoned 0xAA)

  k_cast_X<<<(TT * BB * KP + 255) / 256, 256, 0, stream>>>(X, Xt);
  k_cast_padW<<<(G4 * KP + 255) / 256, 256, 0, stream>>>(Wih0, W0p);
  k_cast<<<(G4 * HH + 255) / 256, 256, 0, stream>>>(Whh0, Whh0h, G4 * HH);
  k_cast<<<(G4 * HH + 255) / 256, 256, 0, stream>>>(Wih1, Wih1h, G4 * HH);
  k_cast<<<(G4 * HH + 255) / 256, 256, 0, stream>>>(Whh1, Whh1h, G4 * HH);
  k_bias<<<(G4 + 255) / 256, 256, 0, stream>>>(bih0, bhh0, bih1, bhh1, b0, b1);

  k_mega<<<256 + NWRK, 512, 0, stream>>>(Xt, W0p, Whh0h, Wih1h, Whh1h, b0, b1,
                                         xg0, xg1, y1, y2, bar);

  k_out<<<(TT * BB) / 4, 256, 0, stream>>>(y2, Wy, by, out);
}

// Round 8
// 1043.571 us; speedup vs baseline: 1.5905x; 1.5905x over previous
//
#include <hip/hip_runtime.h>
#include <stdint.h>

#define BB 64
#define TT 128
#define INF 257
#define KP 288
#define HH 1024
#define G4 4096
#define GLS 20  // gl row stride (floats): pads 4-way bank conflict down to free 2-way

typedef _Float16 half8 __attribute__((ext_vector_type(8)));
typedef float f4 __attribute__((ext_vector_type(4)));

__device__ __forceinline__ f4 mfma16(half8 a, half8 b, f4 c) {
  return __builtin_amdgcn_mfma_f32_16x16x32_f16(a, b, c, 0, 0, 0);
}

// async global->LDS, 16B per lane; LDS dest is wave-uniform base + lane*16
__device__ __forceinline__ void gld_lds16(const void* g, void* l) {
  auto gp = reinterpret_cast<__attribute__((address_space(1))) void*>(reinterpret_cast<uintptr_t>(g));
  auto lp = reinterpret_cast<__attribute__((address_space(3))) void*>(reinterpret_cast<uintptr_t>(l));
  __builtin_amdgcn_global_load_lds(gp, lp, 16, 0, 0);
}

__device__ __forceinline__ unsigned aload(unsigned* p) {
  return __hip_atomic_load(p, __ATOMIC_RELAXED, __HIP_MEMORY_SCOPE_AGENT);
}

// ---------- merged prep: all casts + padding + bias sums in one dispatch ----------
__global__ __launch_bounds__(256) void k_prep(const float* __restrict__ X,
                                              const float* __restrict__ Wih0, const float* __restrict__ Whh0,
                                              const float* __restrict__ Wih1, const float* __restrict__ Whh1,
                                              const float* __restrict__ bih0, const float* __restrict__ bhh0,
                                              const float* __restrict__ bih1, const float* __restrict__ bhh1,
                                              _Float16* __restrict__ Xt, _Float16* __restrict__ W0p,
                                              _Float16* __restrict__ Whh0h, _Float16* __restrict__ Wih1h,
                                              _Float16* __restrict__ Whh1h,
                                              float* __restrict__ b0, float* __restrict__ b1) {
  const int S0 = TT * BB * KP, S1 = G4 * KP, S2 = G4 * HH;
  int o = blockIdx.x * 256 + threadIdx.x;
  if (o < S0) {  // X [B,T,IN] -> Xt [T*B][KP] fp16, zero-padded
    int k = o % KP, m = o / KP;
    int t = m >> 6, b = m & 63;
    Xt[o] = (_Float16)((k < INF) ? X[((size_t)b * TT + t) * INF + k] : 0.f);
    return;
  }
  o -= S0;
  if (o < S1) {  // Wih0 [4H,IN] -> [4H][KP] fp16 padded
    int k = o % KP, n = o / KP;
    W0p[o] = (_Float16)((k < INF) ? Wih0[(size_t)n * INF + k] : 0.f);
    return;
  }
  o -= S1;
  if (o < S2) { Whh0h[o] = (_Float16)Whh0[o]; return; }
  o -= S2;
  if (o < S2) { Wih1h[o] = (_Float16)Wih1[o]; return; }
  o -= S2;
  if (o < S2) { Whh1h[o] = (_Float16)Whh1[o]; return; }
  o -= S2;
  if (o < G4) { b0[o] = bih0[o] + bhh0[o]; b1[o] = bih1[o] + bhh1[o]; }
}

// ---------- big GEMM (layer-0 input projection): C[M,4096] = A@Bw^T + bias ----------
__global__ __launch_bounds__(256) void k_gemm(const _Float16* __restrict__ A, const _Float16* __restrict__ Bw,
                                              const float* __restrict__ bias, _Float16* __restrict__ C,
                                              int K, int lda, int ldb) {
  __shared__ __align__(16) _Float16 As[4 * 128 * 8];
  __shared__ __align__(16) _Float16 Bs[4 * 128 * 8];
  const int tid = threadIdx.x;
  const int w = tid >> 6, lane = tid & 63;
  const int q = lane >> 4, ml = lane & 15;
  const int m0 = blockIdx.x * 128, n0 = blockIdx.y * 128;
  const int wm = (w >> 1) * 64, wn = (w & 1) * 64;
  f4 acc[4][4] = {};
  const int kt_iters = K >> 5;
  for (int kt = 0; kt < kt_iters; ++kt) {
    __syncthreads();
#pragma unroll
    for (int i = 0; i < 2; ++i) {
      int cb = i * 256 + w * 64;
      int kc = cb >> 7, mb = cb & 127;
      gld_lds16(A + (size_t)(m0 + mb + lane) * lda + kt * 32 + kc * 8, (char*)As + (size_t)cb * 16);
      gld_lds16(Bw + (size_t)(n0 + mb + lane) * ldb + kt * 32 + kc * 8, (char*)Bs + (size_t)cb * 16);
    }
    __syncthreads();
    half8 af[4], bf[4];
#pragma unroll
    for (int tm = 0; tm < 4; ++tm) af[tm] = *(const half8*)(As + ((size_t)q * 128 + wm + tm * 16 + ml) * 8);
#pragma unroll
    for (int tn = 0; tn < 4; ++tn) bf[tn] = *(const half8*)(Bs + ((size_t)q * 128 + wn + tn * 16 + ml) * 8);
#pragma unroll
    for (int tm = 0; tm < 4; ++tm)
#pragma unroll
      for (int tn = 0; tn < 4; ++tn)
        acc[tm][tn] = mfma16(af[tm], bf[tn], acc[tm][tn]);
  }
#pragma unroll
  for (int tn = 0; tn < 4; ++tn) {
    int n = n0 + wn + tn * 16 + ml;
    float bv = bias[n];
#pragma unroll
    for (int tm = 0; tm < 4; ++tm)
#pragma unroll
      for (int r = 0; r < 4; ++r) {
        int m = m0 + wm + tm * 16 + q * 4 + r;
        C[(size_t)m * G4 + n] = (_Float16)(acc[tm][tn][r] + bv);
      }
  }
}

// ---------- layer-0 recurrence (128 WGs x 512 thr): gates = xg0[t] + Whh0 @ h ----------
// WG idx: ug = idx&63 (units [ug*16..+16) x 4 gates), mgp = idx>>6 (rows [mgp*32..+32)).
// Wave w = K-eighth of 1024. Release: h exchange (at IC) -> waitcnt -> sync -> bump
// cy1[(mgp, ug>>3)] EVERY step (layer-1 gates on the final one too).
__device__ __forceinline__ void rec_l0(const _Float16* __restrict__ xg, const _Float16* Whh,
                                       _Float16* y, unsigned* cy, int idx, int tid,
                                       float (*gl)[4][32 * GLS]) {
  const int w = tid >> 6, lane = tid & 63;
  const int q = lane >> 4, ml = lane & 15;
  const int ug = idx & 63, mgp = idx >> 6;
  const int u0 = ug * 16, b0 = mgp * 32;
  const int brow = tid >> 4, u = tid & 15;
  const int bi = b0 + brow, col = u0 + u;

  half8 bf[4][4];  // Whh slice: row = tn*HH+u0+ml, k = w*128 + kt*32 + q*8
#pragma unroll
  for (int tn = 0; tn < 4; ++tn)
#pragma unroll
    for (int kt = 0; kt < 4; ++kt)
      bf[tn][kt] = *(const half8*)(Whh + (size_t)(tn * HH + u0 + ml) * HH + w * 128 + kt * 32 + q * 8);

  unsigned* myArr = cy + (size_t)(mgp * 8 + (ug >> 3)) * 64;
  unsigned* mySpin = cy + (size_t)(mgp * 8 + w) * 64;
  float c_reg = 0.f;

  for (int t = 0; t < TT; ++t) {
    const _Float16* xp = xg + ((size_t)t * BB + bi) * G4 + col;  // in flight during spin
    _Float16 xv0 = xp[0], xv1 = xp[HH], xv2 = xp[2 * HH], xv3 = xp[3 * HH];
    f4 acc[4][2] = {};
    if (t > 0) {
      if (lane == 0) {
        unsigned tgt = 8u * (unsigned)t;
        while (aload(mySpin) < tgt) __builtin_amdgcn_s_sleep(1);
      }
      asm volatile("" ::: "memory");
      const _Float16* hp = y + ((size_t)(t - 1) * BB + b0 + ml) * HH + w * 128 + q * 8;
      half8 af[2][4];
#pragma unroll
      for (int tm = 0; tm < 2; ++tm)
#pragma unroll
        for (int kt = 0; kt < 4; ++kt)
          af[tm][kt] = *(const half8*)(hp + (size_t)tm * 16 * HH + kt * 32);
#pragma unroll
      for (int kt = 0; kt < 4; ++kt)
#pragma unroll
        for (int tm = 0; tm < 2; ++tm)
#pragma unroll
          for (int tn = 0; tn < 4; ++tn)
            acc[tn][tm] = mfma16(af[tm][kt], bf[tn][kt], acc[tn][tm]);
    }
#pragma unroll
    for (int tn = 0; tn < 4; ++tn)
#pragma unroll
      for (int tm = 0; tm < 2; ++tm)
#pragma unroll
        for (int r = 0; r < 4; ++r)
          gl[w][tn][(tm * 16 + q * 4 + r) * GLS + ml] = acc[tn][tm][r];
    __syncthreads();

    float g0 = (float)xv0, g1 = (float)xv1, g2 = (float)xv2, g3 = (float)xv3;
#pragma unroll
    for (int kw = 0; kw < 8; ++kw) {
      g0 += gl[kw][0][brow * GLS + u]; g1 += gl[kw][1][brow * GLS + u];
      g2 += gl[kw][2][brow * GLS + u]; g3 += gl[kw][3][brow * GLS + u];
    }
    float I = 1.f / (1.f + __expf(-g0));
    float F = 1.f / (1.f + __expf(-g1));
    float G = tanhf(g2);
    float O = 1.f / (1.f + __expf(-g3));
    c_reg = F * c_reg + I * G;
    unsigned hv = (unsigned)__builtin_bit_cast(unsigned short, (_Float16)(O * tanhf(c_reg)));
    unsigned other = (unsigned)__shfl_xor((int)hv, 1);
    if ((tid & 1) == 0) {  // returning atomic => executes at IC => visible when acked
      unsigned word = hv | (other << 16);
      (void)__hip_atomic_exchange((unsigned*)(y + ((size_t)t * BB + bi) * HH + col), word,
                                  __ATOMIC_RELAXED, __HIP_MEMORY_SCOPE_AGENT);
    }
    __builtin_amdgcn_s_waitcnt(0);
    __syncthreads();
    if (tid == 0) atomicAdd(myArr, 1u);  // ALWAYS (layer-1 needs the t=127 bump)
  }
}

// ---------- layer-1 recurrence: gates = [Wih1|Whh1] @ [y1[t]; y2[t-1]] + b1 ----------
// K=2048 concat; waves 0-3 take y1[t] slices (gated on cy1 >= 8(t+1)), waves 4-7 take
// y2[t-1] slices (own chain, cy2 >= 8t). Serial depth of the whole net: ~129 steps.
__device__ __forceinline__ void rec_l1(const _Float16* Wih1, const _Float16* Whh1,
                                       const float* __restrict__ b1,
                                       const _Float16* __restrict__ y1, _Float16* y2,
                                       unsigned* cy1, unsigned* cy2, int idx, int tid,
                                       float (*gl)[4][32 * GLS]) {
  const int w = tid >> 6, lane = tid & 63;
  const int q = lane >> 4, ml = lane & 15;
  const int ug = idx & 63, mgp = idx >> 6;
  const int u0 = ug * 16, b0 = mgp * 32;
  const int brow = tid >> 4, u = tid & 15;
  const int bi = b0 + brow, col = u0 + u;
  const int ws = w & 3;  // k-slice [ws*256..+256) within Wih1 (w<4) or Whh1 (w>=4)

  const _Float16* Bmat = (w < 4) ? Wih1 : Whh1;
  half8 bf[4][8];
#pragma unroll
  for (int tn = 0; tn < 4; ++tn)
#pragma unroll
    for (int kt = 0; kt < 8; ++kt)
      bf[tn][kt] = *(const half8*)(Bmat + (size_t)(tn * HH + u0 + ml) * HH + ws * 256 + kt * 32 + q * 8);

  const float bv0 = b1[col], bv1 = b1[HH + col], bv2 = b1[2 * HH + col], bv3 = b1[3 * HH + col];
  unsigned* myArr = cy2 + (size_t)(mgp * 8 + (ug >> 3)) * 64;
  unsigned* spinBase = ((w < 4) ? cy1 : cy2) + (size_t)(mgp * 8 + 2 * ws) * 64;
  float c_reg = 0.f;

  for (int t = 0; t < TT; ++t) {
    f4 acc[4][2] = {};
    const bool active = (w < 4) || (t > 0);
    if (active) {
      unsigned tgt = 8u * (unsigned)((w < 4) ? (t + 1) : t);
      for (;;) {  // 2-lane poll (256-col slice spans 2 producer counter-groups)
        unsigned v = (lane < 2) ? aload(spinBase + (size_t)lane * 64) : 0xFFFFFFFFu;
        if (__all((int)(v >= tgt))) break;
        __builtin_amdgcn_s_sleep(1);
      }
      asm volatile("" ::: "memory");
      const _Float16* Asrc = (w < 4) ? (y1 + (size_t)t * BB * HH) : (y2 + (size_t)(t - 1) * BB * HH);
      const _Float16* hp = Asrc + (size_t)(b0 + ml) * HH + ws * 256 + q * 8;
      half8 af[2][8];
#pragma unroll
      for (int tm = 0; tm < 2; ++tm)
#pragma unroll
        for (int kt = 0; kt < 8; ++kt)
          af[tm][kt] = *(const half8*)(hp + (size_t)tm * 16 * HH + kt * 32);
#pragma unroll
      for (int kt = 0; kt < 8; ++kt)
#pragma unroll
        for (int tm = 0; tm < 2; ++tm)
#pragma unroll
          for (int tn = 0; tn < 4; ++tn)
            acc[tn][tm] = mfma16(af[tm][kt], bf[tn][kt], acc[tn][tm]);
    }
#pragma unroll
    for (int tn = 0; tn < 4; ++tn)
#pragma unroll
      for (int tm = 0; tm < 2; ++tm)
#pragma unroll
        for (int r = 0; r < 4; ++r)
          gl[w][tn][(tm * 16 + q * 4 + r) * GLS + ml] = acc[tn][tm][r];
    __syncthreads();

    float g0 = bv0, g1 = bv1, g2 = bv2, g3 = bv3;
#pragma unroll
    for (int kw = 0; kw < 8; ++kw) {
      g0 += gl[kw][0][brow * GLS + u]; g1 += gl[kw][1][brow * GLS + u];
      g2 += gl[kw][2][brow * GLS + u]; g3 += gl[kw][3][brow * GLS + u];
    }
    float I = 1.f / (1.f + __expf(-g0));
    float F = 1.f / (1.f + __expf(-g1));
    float G = tanhf(g2);
    float O = 1.f / (1.f + __expf(-g3));
    c_reg = F * c_reg + I * G;
    unsigned hv = (unsigned)__builtin_bit_cast(unsigned short, (_Float16)(O * tanhf(c_reg)));
    unsigned other = (unsigned)__shfl_xor((int)hv, 1);
    if ((tid & 1) == 0) {
      unsigned word = hv | (other << 16);
      (void)__hip_atomic_exchange((unsigned*)(y2 + ((size_t)t * BB + bi) * HH + col), word,
                                  __ATOMIC_RELAXED, __HIP_MEMORY_SCOPE_AGENT);
    }
    __builtin_amdgcn_s_waitcnt(0);
    __syncthreads();
    if (tid == 0) atomicAdd(myArr, 1u);
  }
}

// ---------- fused both-layer recurrence: 256 blocks = 1/CU, no co-tenants ----------
__global__ __launch_bounds__(512, 1) void k_rec2(const _Float16* __restrict__ xg0,
                                                 const _Float16* Whh0, const _Float16* Wih1,
                                                 const _Float16* Whh1, const float* __restrict__ b1,
                                                 _Float16* y1, _Float16* y2, unsigned* bar) {
  __shared__ __align__(16) float gl[8][4][32 * GLS];  // 80 KB (1 block/CU)
  const int bid = blockIdx.x, tid = threadIdx.x;
  unsigned* cy1 = bar;
  unsigned* cy2 = bar + 1024;
  if (bid < 128)
    rec_l0(xg0, Whh0, y1, cy1, bid, tid, gl);
  else
    rec_l1(Wih1, Whh1, b1, y1, y2, cy1, cy2, bid - 128, tid, gl);
}

// ---------- output head ----------
__global__ __launch_bounds__(256) void k_out(const _Float16* __restrict__ y2, const float* __restrict__ Wy,
                                             const float* __restrict__ by, float* __restrict__ out) {
  int gw = blockIdx.x * 4 + (threadIdx.x >> 6);
  int lane = threadIdx.x & 63;
  int t = gw >> 6, b = gw & 63;
  const _Float16* row = y2 + (size_t)gw * HH;
  float p0 = 0.f, p1 = 0.f;
#pragma unroll
  for (int i = 0; i < 16; ++i) {
    int k = i * 64 + lane;
    float v = tanhf((float)row[k]);
    p0 += v * Wy[k];
    p1 += v * Wy[HH + k];
  }
  for (int off = 32; off > 0; off >>= 1) {
    p0 += __shfl_down(p0, off);
    p1 += __shfl_down(p1, off);
  }
  if (lane == 0) {
    out[((size_t)b * TT + t) * 2 + 0] = p0 + by[0];
    out[((size_t)b * TT + t) * 2 + 1] = p1 + by[1];
  }
}

extern "C" void kernel_launch(void* const* d_in, const int* in_sizes, int n_in,
                              void* d_out, int out_size, void* d_ws, size_t ws_size,
                              hipStream_t stream) {
  (void)in_sizes; (void)n_in; (void)out_size; (void)ws_size;
  const float* X    = (const float*)d_in[0];
  const float* Wih0 = (const float*)d_in[3];
  const float* Whh0 = (const float*)d_in[4];
  const float* bih0 = (const float*)d_in[5];
  const float* bhh0 = (const float*)d_in[6];
  const float* Wih1 = (const float*)d_in[7];
  const float* Whh1 = (const float*)d_in[8];
  const float* bih1 = (const float*)d_in[9];
  const float* bhh1 = (const float*)d_in[10];
  const float* Wy   = (const float*)d_in[11];
  const float* by   = (const float*)d_in[12];
  float* out = (float*)d_out;

  char* p = (char*)d_ws;
  auto carve = [&](size_t bytes) { char* r = p; p += (bytes + 255) & ~(size_t)255; return r; };
  _Float16* Xt    = (_Float16*)carve((size_t)TT * BB * KP * 2);
  _Float16* W0p   = (_Float16*)carve((size_t)G4 * KP * 2);
  _Float16* Whh0h = (_Float16*)carve((size_t)G4 * HH * 2);
  _Float16* Wih1h = (_Float16*)carve((size_t)G4 * HH * 2);
  _Float16* Whh1h = (_Float16*)carve((size_t)G4 * HH * 2);
  float* b0 = (float*)carve((size_t)G4 * 4);
  float* b1 = (float*)carve((size_t)G4 * 4);
  _Float16* xg0 = (_Float16*)carve((size_t)TT * BB * G4 * 2);
  _Float16* y1  = (_Float16*)carve((size_t)TT * BB * HH * 2);
  _Float16* y2  = (_Float16*)carve((size_t)TT * BB * HH * 2);
  unsigned* bar = (unsigned*)carve(8192);  // cy1: 16x256B, cy2: 16x256B

  hipMemsetAsync(bar, 0, 8192, stream);  // counters zero (ws is poisoned 0xAA)

  const int prep_total = TT * BB * KP + G4 * KP + 3 * (G4 * HH) + G4;
  k_prep<<<(prep_total + 255) / 256, 256, 0, stream>>>(X, Wih0, Whh0, Wih1, Whh1,
                                                       bih0, bhh0, bih1, bhh1,
                                                       Xt, W0p, Whh0h, Wih1h, Whh1h, b0, b1);
  k_gemm<<<dim3(TT * BB / 128, G4 / 128), 256, 0, stream>>>(Xt, W0p, b0, xg0, KP, KP, KP);
  k_rec2<<<256, 512, 0, stream>>>(xg0, Whh0h, Wih1h, Whh1h, b1, y1, y2, bar);
  k_out<<<(TT * BB) / 4, 256, 0, stream>>>(y2, Wy, by, out);
}

// Round 9
// 1033.107 us; speedup vs baseline: 1.6067x; 1.0101x over previous
//
#include <hip/hip_runtime.h>
#include <stdint.h>

#define BB 64
#define TT 128
#define INF 257
#define KP 288
#define HH 1024
#define G4 4096
#define GLS 20  // gl row stride (floats)

typedef _Float16 half8 __attribute__((ext_vector_type(8)));
typedef float f4 __attribute__((ext_vector_type(4)));

__device__ __forceinline__ f4 mfma16(half8 a, half8 b, f4 c) {
  return __builtin_amdgcn_mfma_f32_16x16x32_f16(a, b, c, 0, 0, 0);
}

// async global->LDS, 16B per lane; LDS dest is wave-uniform base + lane*16
__device__ __forceinline__ void gld_lds16(const void* g, void* l) {
  auto gp = reinterpret_cast<__attribute__((address_space(1))) void*>(reinterpret_cast<uintptr_t>(g));
  auto lp = reinterpret_cast<__attribute__((address_space(3))) void*>(reinterpret_cast<uintptr_t>(l));
  __builtin_amdgcn_global_load_lds(gp, lp, 16, 0, 0);
}

__device__ __forceinline__ unsigned aload(unsigned* p) {
  return __hip_atomic_load(p, __ATOMIC_RELAXED, __HIP_MEMORY_SCOPE_AGENT);
}

// ---------- merged prep ----------
__global__ __launch_bounds__(256) void k_prep(const float* __restrict__ X,
                                              const float* __restrict__ Wih0, const float* __restrict__ Whh0,
                                              const float* __restrict__ Wih1, const float* __restrict__ Whh1,
                                              const float* __restrict__ bih0, const float* __restrict__ bhh0,
                                              const float* __restrict__ bih1, const float* __restrict__ bhh1,
                                              _Float16* __restrict__ Xt, _Float16* __restrict__ W0p,
                                              _Float16* __restrict__ Whh0h, _Float16* __restrict__ Wih1h,
                                              _Float16* __restrict__ Whh1h,
                                              float* __restrict__ b0, float* __restrict__ b1) {
  const int S0 = TT * BB * KP, S1 = G4 * KP, S2 = G4 * HH;
  int o = blockIdx.x * 256 + threadIdx.x;
  if (o < S0) {
    int k = o % KP, m = o / KP;
    int t = m >> 6, b = m & 63;
    Xt[o] = (_Float16)((k < INF) ? X[((size_t)b * TT + t) * INF + k] : 0.f);
    return;
  }
  o -= S0;
  if (o < S1) {
    int k = o % KP, n = o / KP;
    W0p[o] = (_Float16)((k < INF) ? Wih0[(size_t)n * INF + k] : 0.f);
    return;
  }
  o -= S1;
  if (o < S2) { Whh0h[o] = (_Float16)Whh0[o]; return; }
  o -= S2;
  if (o < S2) { Wih1h[o] = (_Float16)Wih1[o]; return; }
  o -= S2;
  if (o < S2) { Whh1h[o] = (_Float16)Whh1[o]; return; }
  o -= S2;
  if (o < G4) { b0[o] = bih0[o] + bhh0[o]; b1[o] = bih1[o] + bhh1[o]; }
}

// ---------- big GEMM (layer-0 input projection) ----------
__global__ __launch_bounds__(256) void k_gemm(const _Float16* __restrict__ A, const _Float16* __restrict__ Bw,
                                              const float* __restrict__ bias, _Float16* __restrict__ C,
                                              int K, int lda, int ldb) {
  __shared__ __align__(16) _Float16 As[4 * 128 * 8];
  __shared__ __align__(16) _Float16 Bs[4 * 128 * 8];
  const int tid = threadIdx.x;
  const int w = tid >> 6, lane = tid & 63;
  const int q = lane >> 4, ml = lane & 15;
  const int m0 = blockIdx.x * 128, n0 = blockIdx.y * 128;
  const int wm = (w >> 1) * 64, wn = (w & 1) * 64;
  f4 acc[4][4] = {};
  const int kt_iters = K >> 5;
  for (int kt = 0; kt < kt_iters; ++kt) {
    __syncthreads();
#pragma unroll
    for (int i = 0; i < 2; ++i) {
      int cb = i * 256 + w * 64;
      int kc = cb >> 7, mb = cb & 127;
      gld_lds16(A + (size_t)(m0 + mb + lane) * lda + kt * 32 + kc * 8, (char*)As + (size_t)cb * 16);
      gld_lds16(Bw + (size_t)(n0 + mb + lane) * ldb + kt * 32 + kc * 8, (char*)Bs + (size_t)cb * 16);
    }
    __syncthreads();
    half8 af[4], bf[4];
#pragma unroll
    for (int tm = 0; tm < 4; ++tm) af[tm] = *(const half8*)(As + ((size_t)q * 128 + wm + tm * 16 + ml) * 8);
#pragma unroll
    for (int tn = 0; tn < 4; ++tn) bf[tn] = *(const half8*)(Bs + ((size_t)q * 128 + wn + tn * 16 + ml) * 8);
#pragma unroll
    for (int tm = 0; tm < 4; ++tm)
#pragma unroll
      for (int tn = 0; tn < 4; ++tn)
        acc[tm][tn] = mfma16(af[tm], bf[tn], acc[tm][tn]);
  }
#pragma unroll
  for (int tn = 0; tn < 4; ++tn) {
    int n = n0 + wn + tn * 16 + ml;
    float bv = bias[n];
#pragma unroll
    for (int tm = 0; tm < 4; ++tm)
#pragma unroll
      for (int r = 0; r < 4; ++r) {
        int m = m0 + wm + tm * 16 + q * 4 + r;
        C[(size_t)m * G4 + n] = (_Float16)(acc[tm][tn][r] + bv);
      }
  }
}

// ---------- layer-0 recurrence ----------
__device__ __forceinline__ void rec_l0(const _Float16* __restrict__ xg, const _Float16* Whh,
                                       _Float16* y, unsigned* cy, int idx, int tid,
                                       float (*gl)[4][32 * GLS]) {
  const int w = tid >> 6, lane = tid & 63;
  const int q = lane >> 4, ml = lane & 15;
  const int ug = idx & 63, mgp = idx >> 6;
  const int u0 = ug * 16, b0 = mgp * 32;
  const int brow = tid >> 4, u = tid & 15;
  const int bi = b0 + brow, col = u0 + u;

  half8 bf[4][4];  // Whh slice: row = tn*HH+u0+ml, k = w*128 + kt*32 + q*8
#pragma unroll
  for (int tn = 0; tn < 4; ++tn)
#pragma unroll
    for (int kt = 0; kt < 4; ++kt)
      bf[tn][kt] = *(const half8*)(Whh + (size_t)(tn * HH + u0 + ml) * HH + w * 128 + kt * 32 + q * 8);

  unsigned* myArr = cy + (size_t)(mgp * 8 + (ug >> 3)) * 64;
  unsigned* mySpin = cy + (size_t)(mgp * 8 + w) * 64;
  float c_reg = 0.f;

  for (int t = 0; t < TT; ++t) {
    // force B frags live across iterations (kills rematerialization inside the loop)
#pragma unroll
    for (int tn = 0; tn < 4; ++tn)
#pragma unroll
      for (int kt = 0; kt < 4; ++kt) asm volatile("" : "+v"(bf[tn][kt]));

    const _Float16* xp = xg + ((size_t)t * BB + bi) * G4 + col;  // in flight during spin
    _Float16 xv0 = xp[0], xv1 = xp[HH], xv2 = xp[2 * HH], xv3 = xp[3 * HH];
    f4 acc[4][2] = {};
    if (t > 0) {
      if (lane == 0) {
        unsigned tgt = 8u * (unsigned)t;
        while (aload(mySpin) < tgt) __builtin_amdgcn_s_sleep(1);
      }
      asm volatile("" ::: "memory");
      const _Float16* hp = y + ((size_t)(t - 1) * BB + b0 + ml) * HH + w * 128 + q * 8;
      half8 af[2][4];
#pragma unroll
      for (int tm = 0; tm < 2; ++tm)
#pragma unroll
        for (int kt = 0; kt < 4; ++kt)
          af[tm][kt] = *(const half8*)(hp + (size_t)tm * 16 * HH + kt * 32);
#pragma unroll
      for (int kt = 0; kt < 4; ++kt)
#pragma unroll
        for (int tm = 0; tm < 2; ++tm)
#pragma unroll
          for (int tn = 0; tn < 4; ++tn)
            acc[tn][tm] = mfma16(af[tm][kt], bf[tn][kt], acc[tn][tm]);
    }
#pragma unroll
    for (int tn = 0; tn < 4; ++tn)
#pragma unroll
      for (int tm = 0; tm < 2; ++tm)
#pragma unroll
        for (int r = 0; r < 4; ++r)
          gl[w][tn][(tm * 16 + q * 4 + r) * GLS + ml] = acc[tn][tm][r];
    __syncthreads();

    float g0 = (float)xv0, g1 = (float)xv1, g2 = (float)xv2, g3 = (float)xv3;
#pragma unroll
    for (int kw = 0; kw < 8; ++kw) {
      g0 += gl[kw][0][brow * GLS + u]; g1 += gl[kw][1][brow * GLS + u];
      g2 += gl[kw][2][brow * GLS + u]; g3 += gl[kw][3][brow * GLS + u];
    }
    float I = 1.f / (1.f + __expf(-g0));
    float F = 1.f / (1.f + __expf(-g1));
    float G = tanhf(g2);
    float O = 1.f / (1.f + __expf(-g3));
    c_reg = F * c_reg + I * G;
    unsigned hv = (unsigned)__builtin_bit_cast(unsigned short, (_Float16)(O * tanhf(c_reg)));
    unsigned other = (unsigned)__shfl_xor((int)hv, 1);
    if ((tid & 1) == 0) {  // returning atomic => executes at IC => visible when acked
      unsigned word = hv | (other << 16);
      (void)__hip_atomic_exchange((unsigned*)(y + ((size_t)t * BB + bi) * HH + col), word,
                                  __ATOMIC_RELAXED, __HIP_MEMORY_SCOPE_AGENT);
    }
    __builtin_amdgcn_s_waitcnt(0);
    __syncthreads();
    if (tid == 0) atomicAdd(myArr, 1u);  // ALWAYS (layer-1 gates on the t=127 bump too)
  }
}

// ---------- layer-1 recurrence: gates = [Wih1|Whh1] @ [y1[t]; y2[t-1]] + b1 ----------
__device__ __forceinline__ void rec_l1(const _Float16* Wih1, const _Float16* Whh1,
                                       const float* __restrict__ b1,
                                       const _Float16* __restrict__ y1, _Float16* y2,
                                       unsigned* cy1, unsigned* cy2, int idx, int tid,
                                       float (*gl)[4][32 * GLS]) {
  const int w = tid >> 6, lane = tid & 63;
  const int q = lane >> 4, ml = lane & 15;
  const int ug = idx & 63, mgp = idx >> 6;
  const int u0 = ug * 16, b0 = mgp * 32;
  const int brow = tid >> 4, u = tid & 15;
  const int bi = b0 + brow, col = u0 + u;
  const int ws = w & 3;  // k-slice [ws*256..+256) within Wih1 (w<4) or Whh1 (w>=4)

  const _Float16* Bmat = (w < 4) ? Wih1 : Whh1;
  half8 bf[4][8];
#pragma unroll
  for (int tn = 0; tn < 4; ++tn)
#pragma unroll
    for (int kt = 0; kt < 8; ++kt)
      bf[tn][kt] = *(const half8*)(Bmat + (size_t)(tn * HH + u0 + ml) * HH + ws * 256 + kt * 32 + q * 8);

  const float bv0 = b1[col], bv1 = b1[HH + col], bv2 = b1[2 * HH + col], bv3 = b1[3 * HH + col];
  unsigned* myArr = cy2 + (size_t)(mgp * 8 + (ug >> 3)) * 64;
  unsigned* spinBase = ((w < 4) ? cy1 : cy2) + (size_t)(mgp * 8 + 2 * ws) * 64;
  float c_reg = 0.f;

  for (int t = 0; t < TT; ++t) {
    // force B frags live across iterations (VGPR_Count must jump to ~240 — the win signal)
#pragma unroll
    for (int tn = 0; tn < 4; ++tn)
#pragma unroll
      for (int kt = 0; kt < 8; ++kt) asm volatile("" : "+v"(bf[tn][kt]));

    f4 acc[4][2] = {};
    const bool active = (w < 4) || (t > 0);
    if (active) {
      unsigned tgt = 8u * (unsigned)((w < 4) ? (t + 1) : t);
      for (;;) {  // 2-lane poll (256-col slice spans 2 producer counter-groups)
        unsigned v = (lane < 2) ? aload(spinBase + (size_t)lane * 64) : 0xFFFFFFFFu;
        if (__all((int)(v >= tgt))) break;
        __builtin_amdgcn_s_sleep(1);
      }
      asm volatile("" ::: "memory");
      const _Float16* Asrc = (w < 4) ? (y1 + (size_t)t * BB * HH) : (y2 + (size_t)(t - 1) * BB * HH);
      const _Float16* hp = Asrc + (size_t)(b0 + ml) * HH + ws * 256 + q * 8;
      half8 af[2][8];
#pragma unroll
      for (int tm = 0; tm < 2; ++tm)
#pragma unroll
        for (int kt = 0; kt < 8; ++kt)
          af[tm][kt] = *(const half8*)(hp + (size_t)tm * 16 * HH + kt * 32);
#pragma unroll
      for (int kt = 0; kt < 8; ++kt)
#pragma unroll
        for (int tm = 0; tm < 2; ++tm)
#pragma unroll
          for (int tn = 0; tn < 4; ++tn)
            acc[tn][tm] = mfma16(af[tm][kt], bf[tn][kt], acc[tn][tm]);
    }
#pragma unroll
    for (int tn = 0; tn < 4; ++tn)
#pragma unroll
      for (int tm = 0; tm < 2; ++tm)
#pragma unroll
        for (int r = 0; r < 4; ++r)
          gl[w][tn][(tm * 16 + q * 4 + r) * GLS + ml] = acc[tn][tm][r];
    __syncthreads();

    float g0 = bv0, g1 = bv1, g2 = bv2, g3 = bv3;
#pragma unroll
    for (int kw = 0; kw < 8; ++kw) {
      g0 += gl[kw][0][brow * GLS + u]; g1 += gl[kw][1][brow * GLS + u];
      g2 += gl[kw][2][brow * GLS + u]; g3 += gl[kw][3][brow * GLS + u];
    }
    float I = 1.f / (1.f + __expf(-g0));
    float F = 1.f / (1.f + __expf(-g1));
    float G = tanhf(g2);
    float O = 1.f / (1.f + __expf(-g3));
    c_reg = F * c_reg + I * G;
    unsigned hv = (unsigned)__builtin_bit_cast(unsigned short, (_Float16)(O * tanhf(c_reg)));
    unsigned other = (unsigned)__shfl_xor((int)hv, 1);
    if ((tid & 1) == 0) {
      unsigned word = hv | (other << 16);
      (void)__hip_atomic_exchange((unsigned*)(y2 + ((size_t)t * BB + bi) * HH + col), word,
                                  __ATOMIC_RELAXED, __HIP_MEMORY_SCOPE_AGENT);
    }
    __builtin_amdgcn_s_waitcnt(0);
    __syncthreads();
    if (tid == 0) atomicAdd(myArr, 1u);
  }
}

// ---------- fused both-layer recurrence: 256 blocks = 1/CU ----------
__global__ __launch_bounds__(512, 1) void k_rec2(const _Float16* __restrict__ xg0,
                                                 const _Float16* Whh0, const _Float16* Wih1,
                                                 const _Float16* Whh1, const float* __restrict__ b1,
                                                 _Float16* y1, _Float16* y2, unsigned* bar) {
  __shared__ __align__(16) float gl[8][4][32 * GLS];  // 80 KB (1 block/CU)
  const int bid = blockIdx.x, tid = threadIdx.x;
  unsigned* cy1 = bar;
  unsigned* cy2 = bar + 1024;
  if (bid < 128)
    rec_l0(xg0, Whh0, y1, cy1, bid, tid, gl);
  else
    rec_l1(Wih1, Whh1, b1, y1, y2, cy1, cy2, bid - 128, tid, gl);
}

// ---------- output head ----------
__global__ __launch_bounds__(256) void k_out(const _Float16* __restrict__ y2, const float* __restrict__ Wy,
                                             const float* __restrict__ by, float* __restrict__ out) {
  int gw = blockIdx.x * 4 + (threadIdx.x >> 6);
  int lane = threadIdx.x & 63;
  int t = gw >> 6, b = gw & 63;
  const _Float16* row = y2 + (size_t)gw * HH;
  float p0 = 0.f, p1 = 0.f;
#pragma unroll
  for (int i = 0; i < 16; ++i) {
    int k = i * 64 + lane;
    float v = tanhf((float)row[k]);
    p0 += v * Wy[k];
    p1 += v * Wy[HH + k];
  }
  for (int off = 32; off > 0; off >>= 1) {
    p0 += __shfl_down(p0, off);
    p1 += __shfl_down(p1, off);
  }
  if (lane == 0) {
    out[((size_t)b * TT + t) * 2 + 0] = p0 + by[0];
    out[((size_t)b * TT + t) * 2 + 1] = p1 + by[1];
  }
}

extern "C" void kernel_launch(void* const* d_in, const int* in_sizes, int n_in,
                              void* d_out, int out_size, void* d_ws, size_t ws_size,
                              hipStream_t stream) {
  (void)in_sizes; (void)n_in; (void)out_size; (void)ws_size;
  const float* X    = (const float*)d_in[0];
  const float* Wih0 = (const float*)d_in[3];
  const float* Whh0 = (const float*)d_in[4];
  const float* bih0 = (const float*)d_in[5];
  const float* bhh0 = (const float*)d_in[6];
  const float* Wih1 = (const float*)d_in[7];
  const float* Whh1 = (const float*)d_in[8];
  const float* bih1 = (const float*)d_in[9];
  const float* bhh1 = (const float*)d_in[10];
  const float* Wy   = (const float*)d_in[11];
  const float* by   = (const float*)d_in[12];
  float* out = (float*)d_out;

  char* p = (char*)d_ws;
  auto carve = [&](size_t bytes) { char* r = p; p += (bytes + 255) & ~(size_t)255; return r; };
  _Float16* Xt    = (_Float16*)carve((size_t)TT * BB * KP * 2);
  _Float16* W0p   = (_Float16*)carve((size_t)G4 * KP * 2);
  _Float16* Whh0h = (_Float16*)carve((size_t)G4 * HH * 2);
  _Float16* Wih1h = (_Float16*)carve((size_t)G4 * HH * 2);
  _Float16* Whh1h = (_Float16*)carve((size_t)G4 * HH * 2);
  float* b0 = (float*)carve((size_t)G4 * 4);
  float* b1 = (float*)carve((size_t)G4 * 4);
  _Float16* xg0 = (_Float16*)carve((size_t)TT * BB * G4 * 2);
  _Float16* y1  = (_Float16*)carve((size_t)TT * BB * HH * 2);
  _Float16* y2  = (_Float16*)carve((size_t)TT * BB * HH * 2);
  unsigned* bar = (unsigned*)carve(8192);  // cy1: 16x256B, cy2: 16x256B

  hipMemsetAsync(bar, 0, 8192, stream);  // counters zero (ws is poisoned 0xAA)

  const int prep_total = TT * BB * KP + G4 * KP + 3 * (G4 * HH) + G4;
  k_prep<<<(prep_total + 255) / 256, 256, 0, stream>>>(X, Wih0, Whh0, Wih1, Whh1,
                                                       bih0, bhh0, bih1, bhh1,
                                                       Xt, W0p, Whh0h, Wih1h, Whh1h, b0, b1);
  k_gemm<<<dim3(TT * BB / 128, G4 / 128), 256, 0, stream>>>(Xt, W0p, b0, xg0, KP, KP, KP);
  k_rec2<<<256, 512, 0, stream>>>(xg0, Whh0h, Wih1h, Whh1h, b1, y1, y2, bar);
  k_out<<<(TT * BB) / 4, 256, 0, stream>>>(y2, Wy, by, out);
}